// Round 1
// baseline (226.706 us; speedup 1.0000x reference)
//
#include <hip/hip_runtime.h>
#include <hip/hip_bf16.h>

// Gaussians covariance: cov = M M^T, M = R(q_normalized) * diag-ish scales
// (scales broadcast along columns: M[j][k] = R[j][k] * s[k]).
//
// N = 4,000,000 (divisible by 256 -> no tail handling).
// Memory-bound: 28 B in + 36 B out per Gaussian = 256 MB total.
// Strategy: float4 quat loads; LDS-staged scales load; LDS-staged float4
// coalesced output stores.

#define BLOCK 256

__global__ __launch_bounds__(BLOCK) void gaussians_cov_kernel(
    const float4* __restrict__ quat,     // (N,4) as float4
    const float*  __restrict__ scales,   // (N,3)
    float*        __restrict__ out,      // (N,9)
    int n)
{
    __shared__ float s_sc[BLOCK * 3];    // 768 floats staged scales
    __shared__ float s_out[BLOCK * 9];   // 2304 floats staged output

    const int t    = threadIdx.x;
    const int base = blockIdx.x * BLOCK;

    // ---- stage scales: 768 floats = 192 float4, coalesced ----
    // (base*3 floats offset = blockIdx*3072 bytes, 16B-aligned)
    if (t < (BLOCK * 3) / 4) {
        float4 v = ((const float4*)(scales + (size_t)base * 3))[t];
        s_sc[4 * t + 0] = v.x;
        s_sc[4 * t + 1] = v.y;
        s_sc[4 * t + 2] = v.z;
        s_sc[4 * t + 3] = v.w;
    }

    // ---- quaternion: direct coalesced float4 load ----
    const float4 q = quat[(size_t)base + t];

    __syncthreads();

    float r = q.x, x = q.y, y = q.z, z = q.w;
    const float nrm = sqrtf(r * r + x * x + y * y + z * z);
    const float inv = 1.0f / fmaxf(nrm, 1e-12f);
    r *= inv; x *= inv; y *= inv; z *= inv;

    // stride-3 LDS read: odd stride -> <=2-way bank aliasing (free)
    const float sx = s_sc[3 * t + 0];
    const float sy = s_sc[3 * t + 1];
    const float sz = s_sc[3 * t + 2];

    // rotation matrix rows (reference layout)
    const float R00 = 1.0f - 2.0f * (y * y + z * z);
    const float R01 = 2.0f * (x * y - r * z);
    const float R02 = 2.0f * (x * z + r * y);
    const float R10 = 2.0f * (x * y + r * z);
    const float R11 = 1.0f - 2.0f * (x * x + z * z);
    const float R12 = 2.0f * (y * z - r * x);
    const float R20 = 2.0f * (x * z - r * y);
    const float R21 = 2.0f * (y * z + r * x);
    const float R22 = 1.0f - 2.0f * (x * x + y * y);

    // M[j][k] = R[j][k] * s[k]
    const float M00 = R00 * sx, M01 = R01 * sy, M02 = R02 * sz;
    const float M10 = R10 * sx, M11 = R11 * sy, M12 = R12 * sz;
    const float M20 = R20 * sx, M21 = R21 * sy, M22 = R22 * sz;

    // cov[i][k] = sum_j M[i][j] * M[k][j]  (symmetric)
    const float c00 = M00 * M00 + M01 * M01 + M02 * M02;
    const float c01 = M00 * M10 + M01 * M11 + M02 * M12;
    const float c02 = M00 * M20 + M01 * M21 + M02 * M22;
    const float c11 = M10 * M10 + M11 * M11 + M12 * M12;
    const float c12 = M10 * M20 + M11 * M21 + M12 * M22;
    const float c22 = M20 * M20 + M21 * M21 + M22 * M22;

    // stride-9 LDS write: odd stride -> <=2-way aliasing (free)
    float* o = &s_out[9 * t];
    o[0] = c00; o[1] = c01; o[2] = c02;
    o[3] = c01; o[4] = c11; o[5] = c12;
    o[6] = c02; o[7] = c12; o[8] = c22;

    __syncthreads();

    // ---- coalesced float4 store: 2304 floats = 576 float4 per block ----
    float4*       gout = (float4*)(out + (size_t)base * 9);
    const float4* lsrc = (const float4*)s_out;
    #pragma unroll
    for (int k = t; k < (BLOCK * 9) / 4; k += BLOCK) {
        gout[k] = lsrc[k];
    }
}

extern "C" void kernel_launch(void* const* d_in, const int* in_sizes, int n_in,
                              void* d_out, int out_size, void* d_ws, size_t ws_size,
                              hipStream_t stream) {
    const float4* quat   = (const float4*)d_in[0];   // (N,4) fp32
    const float*  scales = (const float*)d_in[1];    // (N,3) fp32
    float*        out    = (float*)d_out;            // (N,3,3) fp32

    const int n = in_sizes[0] / 4;                   // N = 4,000,000
    const int blocks = (n + BLOCK - 1) / BLOCK;      // 15625, exact

    gaussians_cov_kernel<<<blocks, BLOCK, 0, stream>>>(quat, scales, out, n);
}

// Round 3
// 215.780 us; speedup vs baseline: 1.0506x; 1.0506x over previous
//
#include <hip/hip_runtime.h>
#include <hip/hip_bf16.h>

// Gaussians covariance: cov = M M^T, M[j][k] = R(q_norm)[j][k] * s[k].
//
// N = 4,000,000 (divisible by 256 -> no tail handling).
// Memory-bound: 28 B in + 36 B out per Gaussian = 256 MB total, ~41 us at
// 6.3 TB/s. R1 kernel was ~54 us (inferred); this round removes the scales
// LDS round-trip + one barrier, and uses nontemporal loads/stores for the
// pure streaming traffic. Nontemporal builtins need native vector types,
// not HIP_vector_type -> use ext_vector_type(4).

#define BLOCK 256

typedef float v4f __attribute__((ext_vector_type(4)));

__global__ __launch_bounds__(BLOCK) void gaussians_cov_kernel(
    const float* __restrict__ quat,      // (N,4)
    const float* __restrict__ scales,    // (N,3)
    float*       __restrict__ out,       // (N,9)
    int n)
{
    __shared__ float s_out[BLOCK * 9];   // 2304 floats staged output (9 KB)

    const int t    = threadIdx.x;
    const int base = blockIdx.x * BLOCK;
    const size_t g = (size_t)base + t;

    // ---- quaternion: coalesced float4 nontemporal load ----
    const v4f q = __builtin_nontemporal_load((const v4f*)(quat + 4 * g));

    // ---- scales: 3 scalar loads; a wave's 3 loads cover one contiguous
    //      768 B span -> each line fetched once (cache merges) ----
    const float sx = __builtin_nontemporal_load(&scales[3 * g + 0]);
    const float sy = __builtin_nontemporal_load(&scales[3 * g + 1]);
    const float sz = __builtin_nontemporal_load(&scales[3 * g + 2]);

    float r = q.x, x = q.y, y = q.z, z = q.w;
    const float nrm = sqrtf(r * r + x * x + y * y + z * z);
    const float inv = 1.0f / fmaxf(nrm, 1e-12f);
    r *= inv; x *= inv; y *= inv; z *= inv;

    // rotation matrix rows (reference layout)
    const float R00 = 1.0f - 2.0f * (y * y + z * z);
    const float R01 = 2.0f * (x * y - r * z);
    const float R02 = 2.0f * (x * z + r * y);
    const float R10 = 2.0f * (x * y + r * z);
    const float R11 = 1.0f - 2.0f * (x * x + z * z);
    const float R12 = 2.0f * (y * z - r * x);
    const float R20 = 2.0f * (x * z - r * y);
    const float R21 = 2.0f * (y * z + r * x);
    const float R22 = 1.0f - 2.0f * (x * x + y * y);

    // M[j][k] = R[j][k] * s[k]
    const float M00 = R00 * sx, M01 = R01 * sy, M02 = R02 * sz;
    const float M10 = R10 * sx, M11 = R11 * sy, M12 = R12 * sz;
    const float M20 = R20 * sx, M21 = R21 * sy, M22 = R22 * sz;

    // cov[i][k] = sum_j M[i][j] * M[k][j]  (symmetric)
    const float c00 = M00 * M00 + M01 * M01 + M02 * M02;
    const float c01 = M00 * M10 + M01 * M11 + M02 * M12;
    const float c02 = M00 * M20 + M01 * M21 + M02 * M22;
    const float c11 = M10 * M10 + M11 * M11 + M12 * M12;
    const float c12 = M10 * M20 + M11 * M21 + M12 * M22;
    const float c22 = M20 * M20 + M21 * M21 + M22 * M22;

    // stride-9 LDS write: odd stride -> <=2-way bank aliasing (free, m136)
    float* o = &s_out[9 * t];
    o[0] = c00; o[1] = c01; o[2] = c02;
    o[3] = c01; o[4] = c11; o[5] = c12;
    o[6] = c02; o[7] = c12; o[8] = c22;

    __syncthreads();

    // ---- coalesced nontemporal float4 store: 576 float4 per block ----
    float*       gout = out + (size_t)base * 9;
    const v4f*   lsrc = (const v4f*)s_out;
    #pragma unroll
    for (int k = t; k < (BLOCK * 9) / 4; k += BLOCK) {
        __builtin_nontemporal_store(lsrc[k], (v4f*)(gout + 4 * k));
    }
}

extern "C" void kernel_launch(void* const* d_in, const int* in_sizes, int n_in,
                              void* d_out, int out_size, void* d_ws, size_t ws_size,
                              hipStream_t stream) {
    const float* quat   = (const float*)d_in[0];     // (N,4) fp32
    const float* scales = (const float*)d_in[1];     // (N,3) fp32
    float*       out    = (float*)d_out;             // (N,3,3) fp32

    const int n = in_sizes[0] / 4;                   // N = 4,000,000
    const int blocks = (n + BLOCK - 1) / BLOCK;      // 15625, exact

    gaussians_cov_kernel<<<blocks, BLOCK, 0, stream>>>(quat, scales, out, n);
}